// Round 6
// baseline (578.894 us; speedup 1.0000x reference)
//
#include <hip/hip_runtime.h>

// Receiver_46076409152346 — v5: single persistent kernel, software grid barrier.
// Contract: inputs float32, outputs float32.
//
// Collapse identity: pair_left[r,c] = new_state[r>>11, (r>>2)&511] (const per row)
//  => y[bi,rr] = b_y2 + sum_j w_y2[j]*relu(v*ws1[j] + G[rr,j]),
//     v = ns[bi][rr>>2], ws1[j] = sum_{c<512} w_y1[j,c],
//     G[rr,j] = b_y1[j] + sum_c desc[rr,c]*w_y1[j,512+c].
//
// v5 (profile-driven): round 5 showed 8 serialized dispatches each paying a
// 10-15us latency/launch floor for <4us of work, and g_kernel at 49.6us
// (1 wave/SIMD, 1.58M LDS conflicts, 64x16-shfl epilogue). Now: one kernel,
// grid 256 (=1 block/CU, co-resident by capacity), 7 software grid barriers;
// g phase: 512 thr, BK=32, LDS-transposed-G epilogue (no shuffles).

#define NBLK 256
#define SMEM_FLOATS 9696  // 38.8 KB, max over phases (g phase)

struct Params {
  const float *message, *state, *desc;
  const float *w_ih, *w_hh, *b_ih, *b_hh;
  const float *w_stop, *b_stop;
  const float *w_y1, *b_y1, *w_y2, *b_y2;
  const float *w_state, *b_state, *w_desc, *w_msg, *b_msg;
  float *out_stopbit, *out_stopdist, *out_msg, *out_msgdist, *out_y;
  float *ns, *nsT, *ws1, *yp, *scores, *di, *ms;
  int *bar;  // [0]=count, [1]=generation; memset to 0 before each launch
};

__device__ __forceinline__ float sigm(float x) { return 1.0f / (1.0f + expf(-x)); }

// stage a 512-float row into LDS padded to stride 68 per 64-float group
__device__ __forceinline__ void stage_pad68(float* dst, const float* src, int c) {
  *(float4*)&dst[(c >> 4) * 68 + (c & 15) * 4] = *(const float4*)&src[c * 4];
}

// sense-reversing grid barrier (device scope, XCD-safe)
__device__ __forceinline__ void grid_barrier(int* bar) {
  __syncthreads();
  __threadfence();  // publish this block's stores device-wide
  if (threadIdx.x == 0) {
    int* cnt = bar;
    int* gen = bar + 1;
    int g = __hip_atomic_load(gen, __ATOMIC_ACQUIRE, __HIP_MEMORY_SCOPE_AGENT);
    int a = __hip_atomic_fetch_add(cnt, 1, __ATOMIC_ACQ_REL, __HIP_MEMORY_SCOPE_AGENT);
    if (a == NBLK - 1) {
      __hip_atomic_store(cnt, 0, __ATOMIC_RELAXED, __HIP_MEMORY_SCOPE_AGENT);
      __hip_atomic_store(gen, g + 1, __ATOMIC_RELEASE, __HIP_MEMORY_SCOPE_AGENT);
    } else {
      while (__hip_atomic_load(gen, __ATOMIC_ACQUIRE, __HIP_MEMORY_SCOPE_AGENT) == g) {
        __builtin_amdgcn_s_sleep(2);
      }
    }
  }
  __syncthreads();
}

// ---------------- P0: GRU. block handles h = blk and blk+256. (v4-verified map)
__device__ void phase_gru(const Params& P, float* sm, int blk, int t) {
  float* sHr = sm;           // 544
  float* sHz = sm + 544;
  float* sHn = sm + 1088;
  float* sIr = sm + 1632;    // 64
  float* sIz = sm + 1696;
  float* sIn = sm + 1760;
  for (int pass = 0; pass < 2; ++pass) {
    const int h = blk + pass * 256;
    __syncthreads();
    if (t < 128)      stage_pad68(sHr, P.w_hh + h * 512, t);
    else if (t < 256) stage_pad68(sHz, P.w_hh + (h + 512) * 512, t - 128);
    else if (t < 384) stage_pad68(sHn, P.w_hh + (h + 1024) * 512, t - 256);
    else if (t < 400) ((float4*)sIr)[t - 384] = ((const float4*)(P.w_ih + h * 64))[t - 384];
    else if (t < 416) ((float4*)sIz)[t - 400] = ((const float4*)(P.w_ih + (h + 512) * 64))[t - 400];
    else if (t < 432) ((float4*)sIn)[t - 416] = ((const float4*)(P.w_ih + (h + 1024) * 64))[t - 416];
    __syncthreads();
    const int bi = t >> 3, kg = t & 7;
    float pr = 0.f, pz = 0.f, pin = 0.f, phn = 0.f;
    {
      const float* mrow = P.message + bi * 64 + kg * 8;
      const float* ir = &sIr[kg * 8];
      const float* iz = &sIz[kg * 8];
      const float* in_ = &sIn[kg * 8];
      #pragma unroll
      for (int i = 0; i < 2; ++i) {
        float4 x = *(const float4*)&mrow[i * 4];
        float4 wr = *(const float4*)&ir[i * 4];
        float4 wz = *(const float4*)&iz[i * 4];
        float4 wn = *(const float4*)&in_[i * 4];
        pr = fmaf(x.x, wr.x, pr); pr = fmaf(x.y, wr.y, pr); pr = fmaf(x.z, wr.z, pr); pr = fmaf(x.w, wr.w, pr);
        pz = fmaf(x.x, wz.x, pz); pz = fmaf(x.y, wz.y, pz); pz = fmaf(x.z, wz.z, pz); pz = fmaf(x.w, wz.w, pz);
        pin = fmaf(x.x, wn.x, pin); pin = fmaf(x.y, wn.y, pin); pin = fmaf(x.z, wn.z, pin); pin = fmaf(x.w, wn.w, pin);
      }
    }
    {
      const float* srow = P.state + bi * 512 + kg * 64;
      const float* hr = &sHr[kg * 68];
      const float* hz = &sHz[kg * 68];
      const float* hn = &sHn[kg * 68];
      #pragma unroll
      for (int i = 0; i < 16; ++i) {
        float4 x = *(const float4*)&srow[i * 4];
        float4 wr = *(const float4*)&hr[i * 4];
        float4 wz = *(const float4*)&hz[i * 4];
        float4 wn = *(const float4*)&hn[i * 4];
        pr = fmaf(x.x, wr.x, pr); pr = fmaf(x.y, wr.y, pr); pr = fmaf(x.z, wr.z, pr); pr = fmaf(x.w, wr.w, pr);
        pz = fmaf(x.x, wz.x, pz); pz = fmaf(x.y, wz.y, pz); pz = fmaf(x.z, wz.z, pz); pz = fmaf(x.w, wz.w, pz);
        phn = fmaf(x.x, wn.x, phn); phn = fmaf(x.y, wn.y, phn); phn = fmaf(x.z, wn.z, phn); phn = fmaf(x.w, wn.w, phn);
      }
    }
    pr += __shfl_xor(pr, 1, 8); pr += __shfl_xor(pr, 2, 8); pr += __shfl_xor(pr, 4, 8);
    pz += __shfl_xor(pz, 1, 8); pz += __shfl_xor(pz, 2, 8); pz += __shfl_xor(pz, 4, 8);
    pin += __shfl_xor(pin, 1, 8); pin += __shfl_xor(pin, 2, 8); pin += __shfl_xor(pin, 4, 8);
    phn += __shfl_xor(phn, 1, 8); phn += __shfl_xor(phn, 2, 8); phn += __shfl_xor(phn, 4, 8);
    if ((t & 7) == 0) {
      float r = sigm(pr + P.b_ih[h] + P.b_hh[h]);
      float z = sigm(pz + P.b_ih[h + 512] + P.b_hh[h + 512]);
      float n = tanhf(pin + P.b_ih[h + 1024] + r * (phn + P.b_hh[h + 1024]));
      float hp = P.state[bi * 512 + h];
      float v = (1.0f - z) * n + z * hp;
      P.ns[bi * 512 + h] = v;
      P.nsT[h * 64 + bi] = v;
    }
  }
}

// ---------------- P1: ws1 (blocks 0..63) + stop head (block 64). (v4-verified)
__device__ void phase_stopws1(const Params& P, int blk, int t) {
  if (blk < 64) {
    const int j = blk * 8 + (t >> 6);
    const int lane = t & 63;
    const float* row = P.w_y1 + j * 1024 + lane * 8;
    float4 a = *(const float4*)&row[0];
    float4 b = *(const float4*)&row[4];
    float acc = a.x + a.y + a.z + a.w + b.x + b.y + b.z + b.w;
    #pragma unroll
    for (int m = 1; m < 64; m <<= 1) acc += __shfl_xor(acc, m, 64);
    if (lane == 0) P.ws1[j] = acc;
  } else if (blk == 64) {
    const int bi = t >> 3, kg = t & 7;
    const float* row = P.ns + bi * 512 + kg * 64;
    const float* wrow = P.w_stop + kg * 64;
    float acc = 0.f;
    #pragma unroll
    for (int i = 0; i < 16; ++i) {
      float4 r = *(const float4*)&row[i * 4];
      float4 w = *(const float4*)&wrow[i * 4];
      acc = fmaf(r.x, w.x, acc); acc = fmaf(r.y, w.y, acc);
      acc = fmaf(r.z, w.z, acc); acc = fmaf(r.w, w.w, acc);
    }
    acc += __shfl_xor(acc, 1, 8); acc += __shfl_xor(acc, 2, 8); acc += __shfl_xor(acc, 4, 8);
    if ((t & 7) == 0) {
      float sd = sigm(acc + P.b_stop[0]);
      P.out_stopdist[bi] = sd;
      P.out_stopbit[bi] = rintf(sd);
    }
  }
}

// ---------------- P2: G tile (f32 VALU GEMM, BK=32) + fused y via LDS-Gt.
__device__ void phase_g(const Params& P, float* sm, int blk, int t) {
  float* As  = sm;           // 32*68 = 2176
  float* Bs  = sm + 2176;    // 2176
  float* Gt  = sm + 4352;    // 64*65 = 4160  (Gt[j_local][rr_local])
  float* sV  = sm + 8512;    // 16*66 = 1056
  float* sW1 = sm + 9568;    // 64
  float* sW2 = sm + 9632;    // 64  -> total 9696
  const int rr0 = (blk >> 3) * 64;
  const int j0  = (blk & 7) * 64;
  if (t < 256) {
    const int q = t >> 4, pos = (t & 15) * 4;
    *(float4*)&sV[q * 66 + pos] = *(const float4*)&P.nsT[((rr0 >> 2) + q) * 64 + pos];
  }
  if (t < 64) { sW1[t] = P.ws1[j0 + t]; sW2[t] = P.w_y2[j0 + t]; }
  const int lm = t >> 3, lk4 = (t & 7) * 4;
  const int tm2 = (t >> 4) * 2;
  const int tn4 = (t & 15) * 4;
  const float* aptr = P.desc + (rr0 + lm) * 512 + lk4;
  const float* bptr = P.w_y1 + (j0 + lm) * 1024 + 512 + lk4;
  float4 av = *(const float4*)aptr;
  float4 bv = *(const float4*)bptr;
  float acc[2][4] = {};
  for (int k0 = 0; k0 < 512; k0 += 32) {
    __syncthreads();
    As[(lk4 + 0) * 68 + lm] = av.x; As[(lk4 + 1) * 68 + lm] = av.y;
    As[(lk4 + 2) * 68 + lm] = av.z; As[(lk4 + 3) * 68 + lm] = av.w;
    Bs[(lk4 + 0) * 68 + lm] = bv.x; Bs[(lk4 + 1) * 68 + lm] = bv.y;
    Bs[(lk4 + 2) * 68 + lm] = bv.z; Bs[(lk4 + 3) * 68 + lm] = bv.w;
    __syncthreads();
    if (k0 + 32 < 512) {
      av = *(const float4*)(aptr + k0 + 32);
      bv = *(const float4*)(bptr + k0 + 32);
    }
    #pragma unroll
    for (int k = 0; k < 32; ++k) {
      float2 a = *(const float2*)&As[k * 68 + tm2];
      float4 b = *(const float4*)&Bs[k * 68 + tn4];
      acc[0][0] = fmaf(a.x, b.x, acc[0][0]); acc[0][1] = fmaf(a.x, b.y, acc[0][1]);
      acc[0][2] = fmaf(a.x, b.z, acc[0][2]); acc[0][3] = fmaf(a.x, b.w, acc[0][3]);
      acc[1][0] = fmaf(a.y, b.x, acc[1][0]); acc[1][1] = fmaf(a.y, b.y, acc[1][1]);
      acc[1][2] = fmaf(a.y, b.z, acc[1][2]); acc[1][3] = fmaf(a.y, b.w, acc[1][3]);
    }
  }
  {
    float4 by = *(const float4*)&P.b_y1[j0 + tn4];
    acc[0][0] += by.x; acc[0][1] += by.y; acc[0][2] += by.z; acc[0][3] += by.w;
    acc[1][0] += by.x; acc[1][1] += by.y; acc[1][2] += by.z; acc[1][3] += by.w;
  }
  #pragma unroll
  for (int jj = 0; jj < 4; ++jj) {
    Gt[(tn4 + jj) * 65 + tm2 + 0] = acc[0][jj];
    Gt[(tn4 + jj) * 65 + tm2 + 1] = acc[1][jj];
  }
  __syncthreads();
  // epilogue: thread (rr = t&63, g8 = t>>6) covers 8 bi values; zero shuffles.
  const int rr = t & 63, g8 = t >> 6;
  float v[8], p[8];
  #pragma unroll
  for (int q = 0; q < 8; ++q) { v[q] = sV[(rr >> 2) * 66 + g8 + q * 8]; p[q] = 0.f; }
  #pragma unroll 4
  for (int j = 0; j < 64; ++j) {
    float gv = Gt[j * 65 + rr];
    float w1j = sW1[j], w2j = sW2[j];
    #pragma unroll
    for (int q = 0; q < 8; ++q)
      p[q] = fmaf(w2j, fmaxf(fmaf(v[q], w1j, gv), 0.f), p[q]);
  }
  float* ypb = P.yp + (blk & 7) * 131072 + rr0 + rr;
  #pragma unroll
  for (int q = 0; q < 8; ++q) ypb[(g8 + q * 8) * 2048] = p[q];
}

// ---------------- P3: softmax (blocks 0..63), sums 8 y-partials + b_y2.
__device__ void phase_softmax(const Params& P, float* sm, int blk, int t) {
  if (blk >= 64) return;
  float* sy = sm;          // 2048
  float* red = sm + 2048;  // 512
  const int bi = blk;
  const float b = P.b_y2[0];
  float lmax = -3.0e38f;
  for (int i = t; i < 2048; i += 512) {
    const float* p = P.yp + bi * 2048 + i;
    float v = b + p[0] + p[131072] + p[262144] + p[393216]
                + p[524288] + p[655360] + p[786432] + p[917504];
    sy[i] = v;
    P.out_y[bi * 2048 + i] = v;
    lmax = fmaxf(lmax, v);
  }
  red[t] = lmax;
  __syncthreads();
  for (int s = 256; s > 0; s >>= 1) {
    if (t < s) red[t] = fmaxf(red[t], red[t + s]);
    __syncthreads();
  }
  const float mx = red[0];
  __syncthreads();
  float lsum = 0.0f;
  for (int i = t; i < 2048; i += 512) {
    float e = expf(sy[i] - mx);
    sy[i] = e;
    lsum += e;
  }
  red[t] = lsum;
  __syncthreads();
  for (int s = 256; s > 0; s >>= 1) {
    if (t < s) red[t] += red[t + s];
    __syncthreads();
  }
  const float inv = 1.0f / red[0];
  for (int i = t; i < 2048; i += 512) P.scores[bi * 2048 + i] = sy[i] * inv;
}

// ---------------- P4: di partials (blk -> d-tile blk>>5, n-chunk blk&31).
__device__ void phase_dipart(const Params& P, float* sm, int blk, int t) {
  float* sS = sm;          // 64*66 = 4224  (sS[n_local][bi])
  float* sD = sm + 4224;   // 64*68 = 4352  (sD[n_local][d_local])
  const int d0 = (blk >> 5) * 64;
  const int n0 = (blk & 31) * 64;
  {
    const int bi_s = t >> 3, q8 = (t & 7) * 8;
    float4 s0 = *(const float4*)&P.scores[bi_s * 2048 + n0 + q8];
    float4 s1 = *(const float4*)&P.scores[bi_s * 2048 + n0 + q8 + 4];
    sS[(q8 + 0) * 66 + bi_s] = s0.x; sS[(q8 + 1) * 66 + bi_s] = s0.y;
    sS[(q8 + 2) * 66 + bi_s] = s0.z; sS[(q8 + 3) * 66 + bi_s] = s0.w;
    sS[(q8 + 4) * 66 + bi_s] = s1.x; sS[(q8 + 5) * 66 + bi_s] = s1.y;
    sS[(q8 + 6) * 66 + bi_s] = s1.z; sS[(q8 + 7) * 66 + bi_s] = s1.w;
    *(float4*)&sD[bi_s * 68 + q8]     = *(const float4*)&P.desc[(n0 + bi_s) * 512 + d0 + q8];
    *(float4*)&sD[bi_s * 68 + q8 + 4] = *(const float4*)&P.desc[(n0 + bi_s) * 512 + d0 + q8 + 4];
  }
  __syncthreads();
  const int bi0 = (t >> 4) * 2, dd0 = (t & 15) * 4;
  float acc[2][4] = {};
  #pragma unroll 8
  for (int nn = 0; nn < 64; ++nn) {
    float2 a = *(const float2*)&sS[nn * 66 + bi0];
    float4 b = *(const float4*)&sD[nn * 68 + dd0];
    acc[0][0] = fmaf(a.x, b.x, acc[0][0]); acc[0][1] = fmaf(a.x, b.y, acc[0][1]);
    acc[0][2] = fmaf(a.x, b.z, acc[0][2]); acc[0][3] = fmaf(a.x, b.w, acc[0][3]);
    acc[1][0] = fmaf(a.y, b.x, acc[1][0]); acc[1][1] = fmaf(a.y, b.y, acc[1][1]);
    acc[1][2] = fmaf(a.y, b.z, acc[1][2]); acc[1][3] = fmaf(a.y, b.w, acc[1][3]);
  }
  float* base = P.yp + (blk & 31) * 32768;  // yp dead after softmax -> dp
  *(float4*)&base[(bi0 + 0) * 512 + d0 + dd0] = make_float4(acc[0][0], acc[0][1], acc[0][2], acc[0][3]);
  *(float4*)&base[(bi0 + 1) * 512 + d0 + dd0] = make_float4(acc[1][0], acc[1][1], acc[1][2], acc[1][3]);
}

// ---------------- P5: reduce 32 di partials (blocks 0..63).
__device__ void phase_direduce(const Params& P, int blk, int t) {
  if (blk >= 64) return;
  const int idx = blk * 512 + t;
  float acc = 0.0f;
  #pragma unroll 8
  for (int c = 0; c < 32; ++c) acc += P.yp[c * 32768 + idx];
  P.di[idx] = acc;
}

// ---------------- P6: message_state. block handles hj = blk, blk+256.
__device__ void phase_ms(const Params& P, float* sm, int blk, int t) {
  float* sWs = sm;        // 544
  float* sWd = sm + 544;  // 544
  for (int pass = 0; pass < 2; ++pass) {
    const int hj = blk + pass * 256;
    __syncthreads();
    if (t < 128)      stage_pad68(sWs, P.w_state + hj * 512, t);
    else if (t < 256) stage_pad68(sWd, P.w_desc + hj * 512, t - 128);
    __syncthreads();
    const int bi = t >> 3, kg = t & 7;
    const float* nr = P.ns + bi * 512 + kg * 64;
    const float* dr = P.di + bi * 512 + kg * 64;
    const float* wsp = &sWs[kg * 68];
    const float* wdp = &sWd[kg * 68];
    float acc = 0.f;
    #pragma unroll
    for (int i = 0; i < 16; ++i) {
      float4 a = *(const float4*)&nr[i * 4];
      float4 w = *(const float4*)&wsp[i * 4];
      float4 b = *(const float4*)&dr[i * 4];
      float4 u = *(const float4*)&wdp[i * 4];
      acc = fmaf(a.x, w.x, acc); acc = fmaf(a.y, w.y, acc);
      acc = fmaf(a.z, w.z, acc); acc = fmaf(a.w, w.w, acc);
      acc = fmaf(b.x, u.x, acc); acc = fmaf(b.y, u.y, acc);
      acc = fmaf(b.z, u.z, acc); acc = fmaf(b.w, u.w, acc);
    }
    acc += __shfl_xor(acc, 1, 8); acc += __shfl_xor(acc, 2, 8); acc += __shfl_xor(acc, 4, 8);
    if ((t & 7) == 0) P.ms[bi * 512 + hj] = tanhf(acc + P.b_state[hj]);
  }
}

// ---------------- P7: message head (blocks 0..63, m = blk).
__device__ void phase_msg(const Params& P, float* sm, int blk, int t) {
  if (blk >= 64) return;
  float* sW = sm;  // 544
  if (t < 128) stage_pad68(sW, P.w_msg + blk * 512, t);
  __syncthreads();
  const int bi = t >> 3, kg = t & 7;
  const float* row = P.ms + bi * 512 + kg * 64;
  const float* wp = &sW[kg * 68];
  float acc = 0.f;
  #pragma unroll
  for (int i = 0; i < 16; ++i) {
    float4 a = *(const float4*)&row[i * 4];
    float4 w = *(const float4*)&wp[i * 4];
    acc = fmaf(a.x, w.x, acc); acc = fmaf(a.y, w.y, acc);
    acc = fmaf(a.z, w.z, acc); acc = fmaf(a.w, w.w, acc);
  }
  acc += __shfl_xor(acc, 1, 8); acc += __shfl_xor(acc, 2, 8); acc += __shfl_xor(acc, 4, 8);
  if ((t & 7) == 0) {
    float md = sigm(acc + P.b_msg[blk]);
    P.out_msgdist[bi * 64 + blk] = md;
    P.out_msg[bi * 64 + blk] = rintf(md);
  }
}

// ---------------- fused persistent kernel
__global__ __launch_bounds__(512, 1) void fused_kernel(Params P) {
  __shared__ float sm[SMEM_FLOATS];
  const int blk = blockIdx.x, t = threadIdx.x;
  phase_gru(P, sm, blk, t);
  grid_barrier(P.bar);
  phase_stopws1(P, blk, t);
  grid_barrier(P.bar);
  phase_g(P, sm, blk, t);
  grid_barrier(P.bar);
  phase_softmax(P, sm, blk, t);
  grid_barrier(P.bar);
  phase_dipart(P, sm, blk, t);
  grid_barrier(P.bar);
  phase_direduce(P, blk, t);
  grid_barrier(P.bar);
  phase_ms(P, sm, blk, t);
  grid_barrier(P.bar);
  phase_msg(P, sm, blk, t);
}

extern "C" void kernel_launch(void* const* d_in, const int* in_sizes, int n_in,
                              void* d_out, int out_size, void* d_ws, size_t ws_size,
                              hipStream_t stream) {
  (void)in_sizes; (void)n_in; (void)out_size; (void)ws_size;
  float* out = (float*)d_out;
  char* ws = (char*)d_ws;

  Params p;
  p.message = (const float*)d_in[0];
  p.state   = (const float*)d_in[1];
  // d_in[2] "image" unused by the reference.
  p.desc    = (const float*)d_in[3];
  p.w_ih    = (const float*)d_in[4];
  p.w_hh    = (const float*)d_in[5];
  p.b_ih    = (const float*)d_in[6];
  p.b_hh    = (const float*)d_in[7];
  p.w_stop  = (const float*)d_in[8];
  p.b_stop  = (const float*)d_in[9];
  p.w_y1    = (const float*)d_in[10];
  p.b_y1    = (const float*)d_in[11];
  p.w_y2    = (const float*)d_in[12];
  p.b_y2    = (const float*)d_in[13];
  p.w_state = (const float*)d_in[14];
  p.b_state = (const float*)d_in[15];
  p.w_desc  = (const float*)d_in[16];
  p.w_msg   = (const float*)d_in[17];
  p.b_msg   = (const float*)d_in[18];

  p.out_stopbit  = out;          // [64]
  p.out_stopdist = out + 64;     // [64]
  p.out_msg      = out + 128;    // [64*64]
  p.out_msgdist  = out + 4224;   // [64*64]
  p.out_y        = out + 8320;   // [64*2048]

  p.ns     = (float*)(ws);             // 64*512
  p.nsT    = (float*)(ws + 131072);    // 512*64
  p.ws1    = (float*)(ws + 262144);    // 512
  p.yp     = (float*)(ws + 270336);    // 8*64*2048 (reused as di partials)
  p.scores = (float*)(ws + 4988928);   // 64*2048
  p.di     = (float*)(ws + 5513216);   // 64*512
  p.ms     = (float*)(ws + 5644288);   // 64*512
  p.bar    = (int*)(ws + 5775360);     // 2 ints (zeroed below)

  hipMemsetAsync(p.bar, 0, 2 * sizeof(int), stream);
  fused_kernel<<<NBLK, 512, 0, stream>>>(p);
}

// Round 8
// 194.576 us; speedup vs baseline: 2.9751x; 2.9751x over previous
//
#include <hip/hip_runtime.h>

// Receiver_46076409152346 — v6 (resubmitted unchanged; round 7 was an
// infra failure: "MI355X container failed twice" — no signal on this code).
// Multi-kernel (v4 structure) with occupancy- and conflict-fixed g,
// widened y, and merged ws1/stop launches.
// Contract: inputs float32, outputs float32.
//
// Collapse identity: pair_left[r,c] = new_state[r>>11, (r>>2)&511] (const per row)
//  => y[bi,rr] = b_y2 + sum_j w_y2[j]*relu(v*ws1[j] + G[rr,j]),
//     v = ns[bi][rr>>2], ws1[j] = sum_{c<512} w_y1[j,c],
//     G[rr,j] = b_y1[j] + sum_c desc[rr,c]*w_y1[j,512+c].
//
// v6 (profile-driven): v5 persistent kernel regressed 2.7x — agent-scope
// acquire spin loops invalidate per-XCD L2 every poll, cache-poisoning the
// active blocks (FETCH 28MB, VALUBusy 3.7%). Reverted to dispatches.
// g: 512 blocks (2/CU), BK=32, padded LDS. y: 256thr 4-way j-split.

__device__ __forceinline__ float sigm(float x) { return 1.0f / (1.0f + expf(-x)); }

__device__ __forceinline__ void stage_pad68(float* dst, const float* src, int c) {
  *(float4*)&dst[(c >> 4) * 68 + (c & 15) * 4] = *(const float4*)&src[c * 4];
}

// ---------------- K1: GRU (blocks 0..511, h=blk) + ws1 (blocks 512..575).
__global__ __launch_bounds__(512) void gruws1_kernel(
    const float* __restrict__ msg, const float* __restrict__ st,
    const float* __restrict__ w_ih, const float* __restrict__ w_hh,
    const float* __restrict__ b_ih, const float* __restrict__ b_hh,
    const float* __restrict__ w_y1,
    float* __restrict__ ns, float* __restrict__ nsT, float* __restrict__ ws1) {
  const int t = threadIdx.x;
  if (blockIdx.x >= 512) {  // ws1: j = (blk-512)*8 + t>>6
    const int j = (blockIdx.x - 512) * 8 + (t >> 6);
    const int lane = t & 63;
    const float* row = w_y1 + j * 1024 + lane * 8;
    float4 a = *(const float4*)&row[0];
    float4 b = *(const float4*)&row[4];
    float acc = a.x + a.y + a.z + a.w + b.x + b.y + b.z + b.w;
    #pragma unroll
    for (int m = 1; m < 64; m <<= 1) acc += __shfl_xor(acc, m, 64);
    if (lane == 0) ws1[j] = acc;
    return;
  }
  const int h = blockIdx.x;
  __shared__ __align__(16) float sHr[544], sHz[544], sHn[544];
  __shared__ __align__(16) float sIr[64], sIz[64], sIn[64];
  if (t < 128)      stage_pad68(sHr, w_hh + h * 512, t);
  else if (t < 256) stage_pad68(sHz, w_hh + (h + 512) * 512, t - 128);
  else if (t < 384) stage_pad68(sHn, w_hh + (h + 1024) * 512, t - 256);
  else if (t < 400) ((float4*)sIr)[t - 384] = ((const float4*)(w_ih + h * 64))[t - 384];
  else if (t < 416) ((float4*)sIz)[t - 400] = ((const float4*)(w_ih + (h + 512) * 64))[t - 400];
  else if (t < 432) ((float4*)sIn)[t - 416] = ((const float4*)(w_ih + (h + 1024) * 64))[t - 416];
  __syncthreads();
  const int bi = t >> 3, kg = t & 7;
  float pr = 0.f, pz = 0.f, pin = 0.f, phn = 0.f;
  {
    const float* mrow = msg + bi * 64 + kg * 8;
    const float* ir = &sIr[kg * 8];
    const float* iz = &sIz[kg * 8];
    const float* in_ = &sIn[kg * 8];
    #pragma unroll
    for (int i = 0; i < 2; ++i) {
      float4 x = *(const float4*)&mrow[i * 4];
      float4 wr = *(const float4*)&ir[i * 4];
      float4 wz = *(const float4*)&iz[i * 4];
      float4 wn = *(const float4*)&in_[i * 4];
      pr = fmaf(x.x, wr.x, pr); pr = fmaf(x.y, wr.y, pr); pr = fmaf(x.z, wr.z, pr); pr = fmaf(x.w, wr.w, pr);
      pz = fmaf(x.x, wz.x, pz); pz = fmaf(x.y, wz.y, pz); pz = fmaf(x.z, wz.z, pz); pz = fmaf(x.w, wz.w, pz);
      pin = fmaf(x.x, wn.x, pin); pin = fmaf(x.y, wn.y, pin); pin = fmaf(x.z, wn.z, pin); pin = fmaf(x.w, wn.w, pin);
    }
  }
  {
    const float* srow = st + bi * 512 + kg * 64;
    const float* hr = &sHr[kg * 68];
    const float* hz = &sHz[kg * 68];
    const float* hn = &sHn[kg * 68];
    #pragma unroll
    for (int i = 0; i < 16; ++i) {
      float4 x = *(const float4*)&srow[i * 4];
      float4 wr = *(const float4*)&hr[i * 4];
      float4 wz = *(const float4*)&hz[i * 4];
      float4 wn = *(const float4*)&hn[i * 4];
      pr = fmaf(x.x, wr.x, pr); pr = fmaf(x.y, wr.y, pr); pr = fmaf(x.z, wr.z, pr); pr = fmaf(x.w, wr.w, pr);
      pz = fmaf(x.x, wz.x, pz); pz = fmaf(x.y, wz.y, pz); pz = fmaf(x.z, wz.z, pz); pz = fmaf(x.w, wz.w, pz);
      phn = fmaf(x.x, wn.x, phn); phn = fmaf(x.y, wn.y, phn); phn = fmaf(x.z, wn.z, phn); phn = fmaf(x.w, wn.w, phn);
    }
  }
  pr += __shfl_xor(pr, 1, 8); pr += __shfl_xor(pr, 2, 8); pr += __shfl_xor(pr, 4, 8);
  pz += __shfl_xor(pz, 1, 8); pz += __shfl_xor(pz, 2, 8); pz += __shfl_xor(pz, 4, 8);
  pin += __shfl_xor(pin, 1, 8); pin += __shfl_xor(pin, 2, 8); pin += __shfl_xor(pin, 4, 8);
  phn += __shfl_xor(phn, 1, 8); phn += __shfl_xor(phn, 2, 8); phn += __shfl_xor(phn, 4, 8);
  if ((t & 7) == 0) {
    float r = sigm(pr + b_ih[h] + b_hh[h]);
    float z = sigm(pz + b_ih[h + 512] + b_hh[h + 512]);
    float n = tanhf(pin + b_ih[h + 1024] + r * (phn + b_hh[h + 1024]));
    float hp = st[bi * 512 + h];
    float v = (1.0f - z) * n + z * hp;
    ns[bi * 512 + h] = v;
    nsT[h * 64 + bi] = v;
  }
}

// ---------------- K2: G = desc @ w_y1[:,512:]^T + b_y1. 32x64 tiles, BK=32.
// grid (64 rr-tiles, 8 j-tiles) = 512 blocks (2/CU) x 256 thr, 2x4 acc.
__global__ __launch_bounds__(256, 2) void g_kernel(
    const float* __restrict__ desc, const float* __restrict__ w_y1,
    const float* __restrict__ b_y1, float* __restrict__ G) {
  __shared__ __align__(16) float As[32 * 33];  // As[k][row], stride 33
  __shared__ __align__(16) float Bs[32 * 68];  // Bs[k][j],   stride 68
  const int rr0 = blockIdx.x * 32;
  const int j0 = blockIdx.y * 64;
  const int t = threadIdx.x;
  const int lrow = t >> 3;           // 0..31
  const int lk4 = (t & 7) * 4;       // 0,4,...,28
  const int tm2 = (t >> 4) * 2;      // row pair 0..30
  const int tn4 = (t & 15) * 4;      // col quad 0..60
  const float* aptr = desc + (rr0 + lrow) * 512 + lk4;
  const float* bptr0 = w_y1 + (j0 + lrow) * 1024 + 512 + lk4;
  const float* bptr1 = bptr0 + 32 * 1024;
  float4 av = *(const float4*)aptr;
  float4 bv0 = *(const float4*)bptr0;
  float4 bv1 = *(const float4*)bptr1;
  float acc[2][4] = {};
  for (int k0 = 0; k0 < 512; k0 += 32) {
    __syncthreads();
    As[(lk4 + 0) * 33 + lrow] = av.x; As[(lk4 + 1) * 33 + lrow] = av.y;
    As[(lk4 + 2) * 33 + lrow] = av.z; As[(lk4 + 3) * 33 + lrow] = av.w;
    Bs[(lk4 + 0) * 68 + lrow] = bv0.x; Bs[(lk4 + 1) * 68 + lrow] = bv0.y;
    Bs[(lk4 + 2) * 68 + lrow] = bv0.z; Bs[(lk4 + 3) * 68 + lrow] = bv0.w;
    Bs[(lk4 + 0) * 68 + lrow + 32] = bv1.x; Bs[(lk4 + 1) * 68 + lrow + 32] = bv1.y;
    Bs[(lk4 + 2) * 68 + lrow + 32] = bv1.z; Bs[(lk4 + 3) * 68 + lrow + 32] = bv1.w;
    __syncthreads();
    if (k0 + 32 < 512) {
      av = *(const float4*)(aptr + k0 + 32);
      bv0 = *(const float4*)(bptr0 + k0 + 32);
      bv1 = *(const float4*)(bptr1 + k0 + 32);
    }
    #pragma unroll
    for (int k = 0; k < 32; ++k) {
      float a0 = As[k * 33 + tm2];
      float a1 = As[k * 33 + tm2 + 1];
      float4 b = *(const float4*)&Bs[k * 68 + tn4];
      acc[0][0] = fmaf(a0, b.x, acc[0][0]); acc[0][1] = fmaf(a0, b.y, acc[0][1]);
      acc[0][2] = fmaf(a0, b.z, acc[0][2]); acc[0][3] = fmaf(a0, b.w, acc[0][3]);
      acc[1][0] = fmaf(a1, b.x, acc[1][0]); acc[1][1] = fmaf(a1, b.y, acc[1][1]);
      acc[1][2] = fmaf(a1, b.z, acc[1][2]); acc[1][3] = fmaf(a1, b.w, acc[1][3]);
    }
  }
  float4 by = *(const float4*)&b_y1[j0 + tn4];
  float4 r0 = make_float4(acc[0][0] + by.x, acc[0][1] + by.y, acc[0][2] + by.z, acc[0][3] + by.w);
  float4 r1 = make_float4(acc[1][0] + by.x, acc[1][1] + by.y, acc[1][2] + by.z, acc[1][3] + by.w);
  *(float4*)&G[(rr0 + tm2) * 512 + j0 + tn4] = r0;
  *(float4*)&G[(rr0 + tm2 + 1) * 512 + j0 + tn4] = r1;
}

// ---------------- K3: y (blocks 0..2047, rr=blk) + stop (block 2048). 256 thr.
__global__ __launch_bounds__(256) void ystop_kernel(
    const float* __restrict__ nsT, const float* __restrict__ ws1,
    const float* __restrict__ G, const float* __restrict__ w_y2,
    const float* __restrict__ b_y2, float* __restrict__ yf,
    const float* __restrict__ ns, const float* __restrict__ w_stop,
    const float* __restrict__ b_stop, float* __restrict__ out_bit,
    float* __restrict__ out_dist) {
  const int t = threadIdx.x;
  if (blockIdx.x == 2048) {  // stop head: bi = t>>2, kg = t&3 (128 k each)
    const int bi = t >> 2, kg = t & 3;
    const float* row = ns + bi * 512 + kg * 128;
    const float* wrow = w_stop + kg * 128;
    float acc = 0.f;
    #pragma unroll
    for (int i = 0; i < 32; ++i) {
      float4 r = *(const float4*)&row[i * 4];
      float4 w = *(const float4*)&wrow[i * 4];
      acc = fmaf(r.x, w.x, acc); acc = fmaf(r.y, w.y, acc);
      acc = fmaf(r.z, w.z, acc); acc = fmaf(r.w, w.w, acc);
    }
    acc += __shfl_xor(acc, 1, 4); acc += __shfl_xor(acc, 2, 4);
    if (kg == 0) {
      float sd = sigm(acc + b_stop[0]);
      out_dist[bi] = sd;
      out_bit[bi] = rintf(sd);
    }
    return;
  }
  const int rr = blockIdx.x;
  __shared__ __align__(16) float sG[512], sW1[512], sW2[512];
  __shared__ float sp[4 * 72];
  if (t < 128) {
    ((float4*)sG)[t] = ((const float4*)(G + rr * 512))[t];
    ((float4*)sW2)[t] = ((const float4*)w_y2)[t];
  } else {
    ((float4*)sW1)[t - 128] = ((const float4*)ws1)[t - 128];
  }
  __syncthreads();
  const int bi = t & 63, jq = t >> 6;
  const float v = nsT[(rr >> 2) * 64 + bi];
  float acc = 0.0f;
  const float* g = sG + jq * 128;
  const float* w1 = sW1 + jq * 128;
  const float* w2 = sW2 + jq * 128;
  #pragma unroll 4
  for (int j = 0; j < 128; j += 4) {
    float4 gv = *(const float4*)&g[j];
    float4 a1 = *(const float4*)&w1[j];
    float4 a2 = *(const float4*)&w2[j];
    acc = fmaf(a2.x, fmaxf(fmaf(v, a1.x, gv.x), 0.0f), acc);
    acc = fmaf(a2.y, fmaxf(fmaf(v, a1.y, gv.y), 0.0f), acc);
    acc = fmaf(a2.z, fmaxf(fmaf(v, a1.z, gv.z), 0.0f), acc);
    acc = fmaf(a2.w, fmaxf(fmaf(v, a1.w, gv.w), 0.0f), acc);
  }
  sp[jq * 72 + bi] = acc;
  __syncthreads();
  if (t < 64) {
    float y = sp[t] + sp[72 + t] + sp[144 + t] + sp[216 + t] + b_y2[0];
    yf[t * 2048 + rr] = y;
  }
}

// ---------------- K4: softmax rows + f32 y output. block = bi (64), 256 thr.
__global__ __launch_bounds__(256) void softmax_kernel(
    const float* __restrict__ yf, float* __restrict__ scores,
    float* __restrict__ out_y) {
  const int bi = blockIdx.x;
  const int t = threadIdx.x;
  __shared__ float sy[2048];
  __shared__ float red[256];
  float lmax = -3.0e38f;
  for (int i = t; i < 2048; i += 256) {
    float v = yf[bi * 2048 + i];
    sy[i] = v;
    out_y[bi * 2048 + i] = v;
    lmax = fmaxf(lmax, v);
  }
  red[t] = lmax;
  __syncthreads();
  for (int s = 128; s > 0; s >>= 1) {
    if (t < s) red[t] = fmaxf(red[t], red[t + s]);
    __syncthreads();
  }
  const float mx = red[0];
  __syncthreads();
  float lsum = 0.0f;
  for (int i = t; i < 2048; i += 256) {
    float e = expf(sy[i] - mx);
    sy[i] = e;
    lsum += e;
  }
  red[t] = lsum;
  __syncthreads();
  for (int s = 128; s > 0; s >>= 1) {
    if (t < s) red[t] += red[t + s];
    __syncthreads();
  }
  const float inv = 1.0f / red[0];
  for (int i = t; i < 2048; i += 256) scores[bi * 2048 + i] = sy[i] * inv;
}

// ---------------- K5: di partials. grid (8 d-tiles, 32 n-chunks) x 256.
__global__ __launch_bounds__(256) void di_part_kernel(
    const float* __restrict__ scores, const float* __restrict__ desc,
    float* __restrict__ dp) {
  __shared__ __align__(16) float sS[64][64];
  __shared__ __align__(16) float sD[64][64];
  const int d0 = blockIdx.x * 64;
  const int n0 = blockIdx.y * 64;
  const int tid = threadIdx.x;
  {
    const int bi = tid >> 2;
    #pragma unroll
    for (int i = 0; i < 4; ++i) {
      const int kq = (tid & 3) * 4 + i * 16;
      float4 av = *(const float4*)&scores[bi * 2048 + n0 + kq];
      sS[kq + 0][bi] = av.x; sS[kq + 1][bi] = av.y;
      sS[kq + 2][bi] = av.z; sS[kq + 3][bi] = av.w;
    }
  }
  {
    #pragma unroll
    for (int i = 0; i < 4; ++i) {
      const int nn = (tid >> 4) + i * 16;
      const int dq = (tid & 15) * 4;
      *(float4*)&sD[nn][dq] = *(const float4*)&desc[(n0 + nn) * 512 + d0 + dq];
    }
  }
  __syncthreads();
  const int bi0 = (tid >> 4) * 4;
  const int dd0 = (tid & 15) * 4;
  float acc[4][4] = {};
  #pragma unroll 8
  for (int nn = 0; nn < 64; ++nn) {
    float4 a = *(const float4*)&sS[nn][bi0];
    float4 b = *(const float4*)&sD[nn][dd0];
    acc[0][0] = fmaf(a.x, b.x, acc[0][0]); acc[0][1] = fmaf(a.x, b.y, acc[0][1]);
    acc[0][2] = fmaf(a.x, b.z, acc[0][2]); acc[0][3] = fmaf(a.x, b.w, acc[0][3]);
    acc[1][0] = fmaf(a.y, b.x, acc[1][0]); acc[1][1] = fmaf(a.y, b.y, acc[1][1]);
    acc[1][2] = fmaf(a.y, b.z, acc[1][2]); acc[1][3] = fmaf(a.y, b.w, acc[1][3]);
    acc[2][0] = fmaf(a.z, b.x, acc[2][0]); acc[2][1] = fmaf(a.z, b.y, acc[2][1]);
    acc[2][2] = fmaf(a.z, b.z, acc[2][2]); acc[2][3] = fmaf(a.z, b.w, acc[2][3]);
    acc[3][0] = fmaf(a.w, b.x, acc[3][0]); acc[3][1] = fmaf(a.w, b.y, acc[3][1]);
    acc[3][2] = fmaf(a.w, b.z, acc[3][2]); acc[3][3] = fmaf(a.w, b.w, acc[3][3]);
  }
  float* base = dp + blockIdx.y * 32768;
  #pragma unroll
  for (int i = 0; i < 4; ++i)
    #pragma unroll
    for (int j = 0; j < 4; ++j)
      base[(bi0 + i) * 512 + d0 + dd0 + j] = acc[i][j];
}

// ---------------- K6: reduce 32 di partials. 64 blocks x 512.
__global__ __launch_bounds__(512) void di_reduce_kernel(
    const float* __restrict__ dp, float* __restrict__ di) {
  const int idx = blockIdx.x * 512 + threadIdx.x;
  float acc = 0.0f;
  #pragma unroll 8
  for (int c = 0; c < 32; ++c) acc += dp[c * 32768 + idx];
  di[idx] = acc;
}

// ---------------- K7: message_state. block = hj (512), 512 thr (bi,kg).
__global__ __launch_bounds__(512) void ms_kernel(
    const float* __restrict__ ns, const float* __restrict__ di,
    const float* __restrict__ w_state, const float* __restrict__ b_state,
    const float* __restrict__ w_desc, float* __restrict__ ms) {
  const int hj = blockIdx.x;
  const int t = threadIdx.x;
  __shared__ __align__(16) float sWs[544], sWd[544];
  if (t < 128)      stage_pad68(sWs, w_state + hj * 512, t);
  else if (t < 256) stage_pad68(sWd, w_desc + hj * 512, t - 128);
  __syncthreads();
  const int bi = t >> 3, kg = t & 7;
  const float* nr = ns + bi * 512 + kg * 64;
  const float* dr = di + bi * 512 + kg * 64;
  const float* wsp = &sWs[kg * 68];
  const float* wdp = &sWd[kg * 68];
  float acc = 0.f;
  #pragma unroll
  for (int i = 0; i < 16; ++i) {
    float4 a = *(const float4*)&nr[i * 4];
    float4 w = *(const float4*)&wsp[i * 4];
    float4 b = *(const float4*)&dr[i * 4];
    float4 u = *(const float4*)&wdp[i * 4];
    acc = fmaf(a.x, w.x, acc); acc = fmaf(a.y, w.y, acc);
    acc = fmaf(a.z, w.z, acc); acc = fmaf(a.w, w.w, acc);
    acc = fmaf(b.x, u.x, acc); acc = fmaf(b.y, u.y, acc);
    acc = fmaf(b.z, u.z, acc); acc = fmaf(b.w, u.w, acc);
  }
  acc += __shfl_xor(acc, 1, 8); acc += __shfl_xor(acc, 2, 8); acc += __shfl_xor(acc, 4, 8);
  if ((t & 7) == 0) ms[bi * 512 + hj] = tanhf(acc + b_state[hj]);
}

// ---------------- K8: message head. block = m (64), 512 thr (bi,kg).
__global__ __launch_bounds__(512) void msg_kernel(
    const float* __restrict__ ms, const float* __restrict__ w_msg,
    const float* __restrict__ b_msg, float* __restrict__ out_msg,
    float* __restrict__ out_msgdist) {
  const int m = blockIdx.x;
  const int t = threadIdx.x;
  __shared__ __align__(16) float sW[544];
  if (t < 128) stage_pad68(sW, w_msg + m * 512, t);
  __syncthreads();
  const int bi = t >> 3, kg = t & 7;
  const float* row = ms + bi * 512 + kg * 64;
  const float* wp = &sW[kg * 68];
  float acc = 0.f;
  #pragma unroll
  for (int i = 0; i < 16; ++i) {
    float4 a = *(const float4*)&row[i * 4];
    float4 w = *(const float4*)&wp[i * 4];
    acc = fmaf(a.x, w.x, acc); acc = fmaf(a.y, w.y, acc);
    acc = fmaf(a.z, w.z, acc); acc = fmaf(a.w, w.w, acc);
  }
  acc += __shfl_xor(acc, 1, 8); acc += __shfl_xor(acc, 2, 8); acc += __shfl_xor(acc, 4, 8);
  if ((t & 7) == 0) {
    float md = sigm(acc + b_msg[m]);
    out_msgdist[bi * 64 + m] = md;
    out_msg[bi * 64 + m] = rintf(md);
  }
}

extern "C" void kernel_launch(void* const* d_in, const int* in_sizes, int n_in,
                              void* d_out, int out_size, void* d_ws, size_t ws_size,
                              hipStream_t stream) {
  (void)in_sizes; (void)n_in; (void)out_size; (void)ws_size;
  const float* message = (const float*)d_in[0];
  const float* state   = (const float*)d_in[1];
  const float* desc    = (const float*)d_in[3];
  const float* w_ih    = (const float*)d_in[4];
  const float* w_hh    = (const float*)d_in[5];
  const float* b_ih    = (const float*)d_in[6];
  const float* b_hh    = (const float*)d_in[7];
  const float* w_stop  = (const float*)d_in[8];
  const float* b_stop  = (const float*)d_in[9];
  const float* w_y1    = (const float*)d_in[10];
  const float* b_y1    = (const float*)d_in[11];
  const float* w_y2    = (const float*)d_in[12];
  const float* b_y2    = (const float*)d_in[13];
  const float* w_state = (const float*)d_in[14];
  const float* b_state = (const float*)d_in[15];
  const float* w_desc  = (const float*)d_in[16];
  const float* w_msg   = (const float*)d_in[17];
  const float* b_msg   = (const float*)d_in[18];

  float* out = (float*)d_out;
  float* out_stopbit  = out;          // [64]
  float* out_stopdist = out + 64;     // [64]
  float* out_msg      = out + 128;    // [64*64]
  float* out_msgdist  = out + 4224;   // [64*64]
  float* out_y        = out + 8320;   // [64*2048]

  char* ws = (char*)d_ws;
  float* ns     = (float*)(ws);             // 64*512
  float* nsT    = (float*)(ws + 131072);    // 512*64
  float* ws1    = (float*)(ws + 262144);    // 512
  float* G      = (float*)(ws + 264192);    // 2048*512 (reused as di partials)
  float* yf     = (float*)(ws + 4458496);   // 64*2048
  float* scores = (float*)(ws + 4982784);   // 64*2048
  float* di     = (float*)(ws + 5507072);   // 64*512
  float* ms     = (float*)(ws + 5638144);   // 64*512

  gruws1_kernel<<<576, 512, 0, stream>>>(message, state, w_ih, w_hh, b_ih, b_hh,
                                         w_y1, ns, nsT, ws1);
  g_kernel<<<dim3(64, 8), 256, 0, stream>>>(desc, w_y1, b_y1, G);
  ystop_kernel<<<2049, 256, 0, stream>>>(nsT, ws1, G, w_y2, b_y2, yf,
                                         ns, w_stop, b_stop, out_stopbit, out_stopdist);
  softmax_kernel<<<64, 256, 0, stream>>>(yf, scores, out_y);
  di_part_kernel<<<dim3(8, 32), 256, 0, stream>>>(scores, desc, G);  // G dead -> dp
  di_reduce_kernel<<<64, 512, 0, stream>>>(G, di);
  ms_kernel<<<512, 512, 0, stream>>>(ns, di, w_state, b_state, w_desc, ms);
  msg_kernel<<<64, 512, 0, stream>>>(ms, w_msg, b_msg, out_msg, out_msgdist);
}